// Round 5
// baseline (129.781 us; speedup 1.0000x reference)
//
#include <hip/hip_runtime.h>

// CNN encoder as implicit-im2col GEMM:
//   A(M=32*2040, K=1024) x Wp(K=1024, N=256), Wp[fd][k] = filt[fd]*W_k[fd][k]
//   out = relu(A*Wp + b_k)
// Round 13: wave K-offset STAGGER on the R10 base. Evidence from R8-R12:
// per-SIMD MFMA demand is ~1033 cyc/kstep in every geometry but the period
// is always 3600-4500 -> latency-bound with ALL pipes <30%. Cause: the 4
// waves/SIMD run the identical loop in phase (no barriers), so they stall
// simultaneously and the SIMD idles; all 512 blocks also read the SAME 8 KB
// of wp3 each kstep (512-way L2 fan-out). Fix: K-sum is order-independent,
// so wave w in block b starts its chunk walk at c0 = ((b&7)*4 + w*2) & 31:
// 16-way wave phase diversity + 8-way XCD spread of the wp3 hot set.
// Everything else is exactly R10 (barrier-free, B global->reg from L2,
// fragment-order wp3, ping-pong prefetch, 64x64 wave tiles, 16 waves/CU).

#define L_SZ   2048
#define NWIN   2040   // L - F (reference uses L - F)
#define BM     128
#define MT     16

typedef __attribute__((ext_vector_type(8)))  short bf16x8;
typedef __attribute__((ext_vector_type(4)))  short bf16x4;
typedef __attribute__((ext_vector_type(16))) float f32x16;

static __device__ __forceinline__ short f2bf(float f) {
    union { float f; unsigned u; } v; v.f = f;
    unsigned r = v.u + 0x7FFFu + ((v.u >> 16) & 1u);
    return (short)(r >> 16);
}

// ---- prep: wp3[c][nb][c8][l32][8 shorts], 32768 slots of 16 B = 512 KB.
// Slot (c, nb, c8, l32) holds Wp[c*32 + c8*8 + jj][nb*32 + l32], jj=0..7,
// with Wp[k][n] = Wk[k][n]*filt[k]. This is exactly the 32x32x16 bf16 MFMA
// B-fragment order: a wave's b[ks][j] is ONE contiguous 1 KB dwordx4 read
// (lanes 0..31 -> c8=2ks (k-half 0), lanes 32..63 -> c8=2ks+1 (k-half 1)).
__global__ __launch_bounds__(256) void prep_w_kernel(
    const float* __restrict__ Wk, const float* __restrict__ filt,
    short* __restrict__ wp3)
{
    int g   = blockIdx.x * 256 + threadIdx.x;  // 32768 slots
    int c   = g >> 10;          // K-chunk 0..31
    int nb  = (g >> 7) & 7;     // 32-col block 0..7
    int c8  = (g >> 5) & 3;     // 8-k subgroup 0..3
    int l32 = g & 31;
    int np  = nb * 32 + l32;
    int kb  = c * 32 + c8 * 8;
    bf16x8 o;
    #pragma unroll
    for (int jj = 0; jj < 8; ++jj)
        o[jj] = f2bf(Wk[(size_t)(kb + jj) * 256 + np] * filt[kb + jj]);
    *reinterpret_cast<bf16x8*>(&wp3[(size_t)g * 8]) = o;
}

__global__ __launch_bounds__(512, 4) void cnn_enc_kernel(
    const float* __restrict__ ub, const short* __restrict__ wp3,
    const float* __restrict__ bk, float* __restrict__ out)
{
    // A slab: 135 rows x 128 d bf16, stride 136 (32-row a-frag b128 reads
    // land 8 accesses/bank = balanced). Only LDS user: 36720 B.
    __shared__ short sA[135 * 136];

    const int tid   = threadIdx.x;
    const int bid   = blockIdx.x;
    const int mt    = bid & 15;          // M-tile
    const int batch = bid >> 4;          // 0..31
    const int l0    = mt * BM;

    const int lane = tid & 63;
    const int wave = tid >> 6;     // 0..7
    const int wm   = wave >> 2;    // 0..1  (64-row sub-tile)
    const int wn   = wave & 3;     // 0..3  (64-col sub-tile)
    const int l32  = lane & 31;
    const int half = lane >> 5;    // 0..1

    // K-chunk starting offset: 8-way across blocks (XCD L2 spread) +
    // 16-way across waves (SIMD phase diversity). K-sum order-independent.
    const int c0 = (((bid & 7) << 2) + (wave << 1)) & 31;

    // ---- prologue: stage all of A (split load / convert+write) ----------
    const float* ubb = ub + ((size_t)batch << 18);  // batch*2048*128
    float4 av[9];                                    // 4320 float4 / 512 thr
    #pragma unroll
    for (int u = 0; u < 9; ++u) {
        int idx = tid + u * 512;
        if (u < 8 || idx < 4320) {
            int r  = idx >> 5;             // row 0..134
            int c4 = idx & 31;             // float4 within row
            int rg = l0 + r; if (rg > L_SZ - 1) rg = L_SZ - 1;
            av[u] = *reinterpret_cast<const float4*>(
                ubb + ((size_t)rg << 7) + c4 * 4);
        }
    }
    #pragma unroll
    for (int u = 0; u < 9; ++u) {
        int idx = tid + u * 512;
        if (u < 8 || idx < 4320) {
            int r  = idx >> 5;
            int c4 = idx & 31;
            bf16x4 o;
            o.x = f2bf(av[u].x); o.y = f2bf(av[u].y);
            o.z = f2bf(av[u].z); o.w = f2bf(av[u].w);
            *reinterpret_cast<bf16x4*>(&sA[r * 136 + c4 * 4]) = o;
        }
    }

    f32x16 acc[2][2];
    #pragma unroll
    for (int i = 0; i < 2; ++i)
        #pragma unroll
        for (int j = 0; j < 2; ++j)
            acc[i][j] = (f32x16){0.f,0.f,0.f,0.f,0.f,0.f,0.f,0.f,
                                 0.f,0.f,0.f,0.f,0.f,0.f,0.f,0.f};

    // a-frag base offsets (shorts): row = wm*64 + i*32 + l32 (+f later),
    // d = ds*32 + ks*16 + half*8
    int aoff[2];
    #pragma unroll
    for (int i = 0; i < 2; ++i)
        aoff[i] = (wm * 64 + i * 32 + l32) * 136 + half * 8;

    // b-frag source: wb + c*8192 + j*1024 + ks*512 (shorts), one dwordx4/lane
    const short* wb = wp3 + (size_t)(wn * 2) * 1024 + (size_t)lane * 8;
    auto loadB = [&](bf16x8 (&b)[2][2], int c) {
        #pragma unroll
        for (int ks = 0; ks < 2; ++ks)
            #pragma unroll
            for (int j = 0; j < 2; ++j)
                b[ks][j] = *reinterpret_cast<const bf16x8*>(
                    wb + (size_t)c * 8192 + j * 1024 + ks * 512);
    };

    auto kstep = [&](int c, bf16x8 (&b)[2][2]) {
        const int f = c >> 2, ds = c & 3;
        bf16x8 a[2][2];                             // [ks][i]
        #pragma unroll
        for (int ks = 0; ks < 2; ++ks)
            #pragma unroll
            for (int i = 0; i < 2; ++i)
                a[ks][i] = *reinterpret_cast<const bf16x8*>(
                    &sA[aoff[i] + f * 136 + ds * 32 + ks * 16]);
        __builtin_amdgcn_s_setprio(1);
        #pragma unroll
        for (int ks = 0; ks < 2; ++ks)
            #pragma unroll
            for (int i = 0; i < 2; ++i)
                #pragma unroll
                for (int j = 0; j < 2; ++j)
                    acc[i][j] = __builtin_amdgcn_mfma_f32_32x32x16_bf16(
                        a[ks][i], b[ks][j], acc[i][j], 0, 0, 0);
        __builtin_amdgcn_s_setprio(0);
    };

    bf16x8 bA[2][2], bB[2][2];
    loadB(bA, c0);                // lands while waves sit at the barrier
    __syncthreads();              // the ONLY barrier: sA visible, then free-run

    #pragma unroll 1
    for (int t = 0; t < 32; t += 2) {
        const int ca = (c0 + t)     & 31;
        const int cb = (c0 + t + 1) & 31;
        const int cn = (c0 + t + 2) & 31;
        loadB(bB, cb);            // prefetch distance ~1 half-iter
        kstep(ca, bA);
        if (t < 30) loadB(bA, cn);
        kstep(cb, bB);
    }

    // ---- epilogue: bias + relu, streaming stores
    // C/D 32x32: col = lane&31, row = (reg&3) + 8*(reg>>2) + 4*(lane>>5)
    #pragma unroll
    for (int j = 0; j < 2; ++j) {
        int n_glob = wn * 64 + j * 32 + l32;
        float bias = bk[n_glob];
        #pragma unroll
        for (int i = 0; i < 2; ++i) {
            #pragma unroll
            for (int r = 0; r < 16; ++r) {
                int row = (r & 3) + 8 * (r >> 2) + 4 * half;
                int l = l0 + wm * 64 + i * 32 + row;
                if (l < NWIN) {
                    float v = acc[i][j][r] + bias;
                    __builtin_nontemporal_store(
                        v > 0.f ? v : 0.f,
                        &out[((size_t)batch * NWIN + l) * 256 + n_glob]);
                }
            }
        }
    }
}

extern "C" void kernel_launch(void* const* d_in, const int* in_sizes, int n_in,
                              void* d_out, int out_size, void* d_ws, size_t ws_size,
                              hipStream_t stream) {
    const float* ub   = (const float*)d_in[0];  // (32,2048,128) fp32
    const float* filt = (const float*)d_in[1];  // (8,128) fp32
    const float* Wk   = (const float*)d_in[2];  // (1024,256) fp32
    const float* bk   = (const float*)d_in[3];  // (256,) fp32
    float* out = (float*)d_out;                 // (32,2040,256) fp32
    short* wp3 = (short*)d_ws;                  // 512 KB fragment-order Wp

    hipLaunchKernelGGL(prep_w_kernel, dim3(128), dim3(256), 0, stream,
                       Wk, filt, wp3);
    hipLaunchKernelGGL(cnn_enc_kernel, dim3(32 * MT), dim3(512), 0, stream,
                       ub, wp3, bk, out);
}

// Round 6
// 124.692 us; speedup vs baseline: 1.0408x; 1.0408x over previous
//
#include <hip/hip_runtime.h>

// CNN encoder as implicit-im2col GEMM:
//   A(M=32*2040, K=1024) x Wp(K=1024, N=256), Wp[fd][k] = filt[fd]*W_k[fd][k]
//   out = relu(A*Wp + b_k)
// Round 14: fine-phase pipelined K-loop (T3+T4 done properly). R8's 2-phase
// loop sits at the documented 2-phase ceiling (705 TF-eq ~= m233's 607-682);
// R9 reproduced m196's "coarse split hurts" (-6%). This round uses the m201
// phase principle: BK=16 micro-chunks, ring of 4 x 8KB sB buffers (3 chunks
// in flight), per iter: {4 ds_read_b128 -> vmcnt(1) -> s_barrier -> issue
// ONE gload_lds (chunk c+3) -> lgkm wait -> setprio + 4 MFMA}. vmcnt is
// never 0 in steady state; one barrier per small phase keeps waves
// role-split (T5 pays per m218b). wp re-tiled to BK=16 fragment order:
// b-frag ds_reads are lane-contiguous (conflict-free).

#define L_SZ   2048
#define NWIN   2040   // L - F (reference uses L - F)
#define BM     128
#define MT     16

typedef __attribute__((ext_vector_type(8)))  short bf16x8;
typedef __attribute__((ext_vector_type(4)))  short bf16x4;
typedef __attribute__((ext_vector_type(16))) float f32x16;

static __device__ __forceinline__ short f2bf(float f) {
    union { float f; unsigned u; } v; v.f = f;
    unsigned r = v.u + 0x7FFFu + ((v.u >> 16) & 1u);
    return (short)(r >> 16);
}

static __device__ __forceinline__ void gload_lds16(const short* g, short* l) {
    __builtin_amdgcn_global_load_lds(
        (const __attribute__((address_space(1))) unsigned int*)g,
        (__attribute__((address_space(3))) unsigned int*)l, 16, 0, 0);
}

// ---- prep: wp4[c16][slot][8 shorts], c16 in [0,64) BK=16 chunks of 8 KB,
// slot = half*256 + n (512 slots/chunk). Slot content: Wp[c16*16 + half*8
// + jj][n], jj=0..7, Wp[k][n] = Wk[k][n]*filt[k]. This is the 32x32x16 bf16
// B-fragment order: staging is lane-linear (slot = tid), and a wave's b-frag
// read j is 64 contiguous slots (lanes 0..31 -> half 0, 32..63 -> half 1),
// i.e. conflict-free ds_read_b128.
__global__ __launch_bounds__(256) void prep_w_kernel(
    const float* __restrict__ Wk, const float* __restrict__ filt,
    short* __restrict__ wp4)
{
    int g    = blockIdx.x * 256 + threadIdx.x;  // 32768 slots
    int c16  = g >> 9;          // chunk 0..63
    int s    = g & 511;
    int half = s >> 8;
    int n    = s & 255;
    int kb   = c16 * 16 + half * 8;
    bf16x8 o;
    #pragma unroll
    for (int jj = 0; jj < 8; ++jj)
        o[jj] = f2bf(Wk[(size_t)(kb + jj) * 256 + n] * filt[kb + jj]);
    *reinterpret_cast<bf16x8*>(&wp4[(size_t)g * 8]) = o;
}

__global__ __launch_bounds__(512, 4) void cnn_enc_kernel(
    const float* __restrict__ ub, const short* __restrict__ wp4,
    const float* __restrict__ bk, float* __restrict__ out)
{
    // A slab: 135 rows x 128 d bf16, stride 136 (32-row a-frag b128 reads
    // land 4 dwords/bank = balanced).
    __shared__ short sA[135 * 136];    // 36720 B
    // B: ring of 4 chunk buffers, 8 KB each (BK=16), lane-linear staged.
    __shared__ short sB[4 * 4096];     // 32768 B  (total 69488 -> 2 blk/CU)

    const int tid   = threadIdx.x;
    const int bid   = blockIdx.x;
    const int mt    = bid & 15;          // M-tile
    const int batch = bid >> 4;          // 0..31
    const int l0    = mt * BM;

    const int lane = tid & 63;
    const int wave = tid >> 6;     // 0..7
    const int wm   = wave >> 2;    // 0..1  (64-row sub-tile)
    const int wn   = wave & 3;     // 0..3  (64-col sub-tile)
    const int l32  = lane & 31;
    const int half = lane >> 5;    // 0..1

    // ---- B chunk staging: 8 KB lane-linear, ONE gload_lds per thread.
    // LDS base is wave-uniform; lane scatter is base + lane*16 (HW rule).
    auto stageB = [&](int c) {
        const short* src = wp4 + (size_t)c * 4096 + (size_t)(wave * 64 + lane) * 8;
        gload_lds16(src, &sB[(c & 3) * 4096 + wave * 512]);
    };

    // ---- prologue: issue A loads, then B chunks 0..2, then convert+write A
    const float* ubb = ub + ((size_t)batch << 18);  // batch*2048*128
    float4 av[9];                                    // 4320 float4 / 512 thr
    #pragma unroll
    for (int u = 0; u < 9; ++u) {
        int idx = tid + u * 512;
        if (u < 8 || idx < 4320) {
            int r  = idx >> 5;             // row 0..134
            int c4 = idx & 31;             // float4 within row
            int rg = l0 + r; if (rg > L_SZ - 1) rg = L_SZ - 1;
            av[u] = *reinterpret_cast<const float4*>(
                ubb + ((size_t)rg << 7) + c4 * 4);
        }
    }
    stageB(0); stageB(1); stageB(2);
    #pragma unroll
    for (int u = 0; u < 9; ++u) {
        int idx = tid + u * 512;
        if (u < 8 || idx < 4320) {
            int r  = idx >> 5;
            int c4 = idx & 31;
            bf16x4 o;
            o.x = f2bf(av[u].x); o.y = f2bf(av[u].y);
            o.z = f2bf(av[u].z); o.w = f2bf(av[u].w);
            *reinterpret_cast<bf16x4*>(&sA[r * 136 + c4 * 4]) = o;
        }
    }

    f32x16 acc[2][2];
    #pragma unroll
    for (int i = 0; i < 2; ++i)
        #pragma unroll
        for (int j = 0; j < 2; ++j)
            acc[i][j] = (f32x16){0.f,0.f,0.f,0.f,0.f,0.f,0.f,0.f,
                                 0.f,0.f,0.f,0.f,0.f,0.f,0.f,0.f};

    // a-frag base (shorts): row = wm*64 + i*32 + l32 (+f later), d = half*8
    int aoff[2];
    #pragma unroll
    for (int i = 0; i < 2; ++i)
        aoff[i] = (wm * 64 + i * 32 + l32) * 136 + half * 8;
    // b-frag base (shorts) within a chunk buffer: slot = half*256 + wn*64
    // + j*32 + l32 -> offset slot*8 (+ j*256)
    const int boff = (half * 256 + wn * 64 + l32) * 8;

    // A writes visible, chunk 0 landed (chunks 1,2 still in flight).
    asm volatile("s_waitcnt vmcnt(2) lgkmcnt(0)" ::: "memory");
    __builtin_amdgcn_s_barrier();
    __builtin_amdgcn_sched_barrier(0);

    // steady state entering iter c: chunk c published; c+1, c+2 issued.
    // iter c: reads(c) -> vmcnt(1) [chunk c+1 done] -> barrier [publish c+1]
    //         -> stage(c+3) -> 4 MFMA. vmcnt never 0 until the tail.
    #pragma unroll 1
    for (int c = 0; c < 64; ++c) {
        const int f = c >> 3, dsub = c & 7;
        const int bb = (c & 3) * 4096;
        bf16x8 a0 = *reinterpret_cast<const bf16x8*>(
            &sA[aoff[0] + f * 136 + dsub * 16]);
        bf16x8 a1 = *reinterpret_cast<const bf16x8*>(
            &sA[aoff[1] + f * 136 + dsub * 16]);
        bf16x8 b0 = *reinterpret_cast<const bf16x8*>(&sB[bb + boff]);
        bf16x8 b1 = *reinterpret_cast<const bf16x8*>(&sB[bb + boff + 256]);
        if (c < 63) {
            if (c < 62) asm volatile("s_waitcnt vmcnt(1)" ::: "memory");
            else        asm volatile("s_waitcnt vmcnt(0)" ::: "memory");
            __builtin_amdgcn_s_barrier();
            __builtin_amdgcn_sched_barrier(0);
            if (c < 61) stageB(c + 3);
        }
        __builtin_amdgcn_s_setprio(1);
        acc[0][0] = __builtin_amdgcn_mfma_f32_32x32x16_bf16(a0, b0, acc[0][0], 0, 0, 0);
        acc[0][1] = __builtin_amdgcn_mfma_f32_32x32x16_bf16(a0, b1, acc[0][1], 0, 0, 0);
        acc[1][0] = __builtin_amdgcn_mfma_f32_32x32x16_bf16(a1, b0, acc[1][0], 0, 0, 0);
        acc[1][1] = __builtin_amdgcn_mfma_f32_32x32x16_bf16(a1, b1, acc[1][1], 0, 0, 0);
        __builtin_amdgcn_s_setprio(0);
    }

    // ---- epilogue: bias + relu, streaming stores
    // C/D 32x32: col = lane&31, row = (reg&3) + 8*(reg>>2) + 4*(lane>>5)
    #pragma unroll
    for (int j = 0; j < 2; ++j) {
        int n_glob = wn * 64 + j * 32 + l32;
        float bias = bk[n_glob];
        #pragma unroll
        for (int i = 0; i < 2; ++i) {
            #pragma unroll
            for (int r = 0; r < 16; ++r) {
                int row = (r & 3) + 8 * (r >> 2) + 4 * half;
                int l = l0 + wm * 64 + i * 32 + row;
                if (l < NWIN) {
                    float v = acc[i][j][r] + bias;
                    __builtin_nontemporal_store(
                        v > 0.f ? v : 0.f,
                        &out[((size_t)batch * NWIN + l) * 256 + n_glob]);
                }
            }
        }
    }
}

extern "C" void kernel_launch(void* const* d_in, const int* in_sizes, int n_in,
                              void* d_out, int out_size, void* d_ws, size_t ws_size,
                              hipStream_t stream) {
    const float* ub   = (const float*)d_in[0];  // (32,2048,128) fp32
    const float* filt = (const float*)d_in[1];  // (8,128) fp32
    const float* Wk   = (const float*)d_in[2];  // (1024,256) fp32
    const float* bk   = (const float*)d_in[3];  // (256,) fp32
    float* out = (float*)d_out;                 // (32,2040,256) fp32
    short* wp4 = (short*)d_ws;                  // 512 KB BK=16 fragment-order Wp

    hipLaunchKernelGGL(prep_w_kernel, dim3(128), dim3(256), 0, stream,
                       Wk, filt, wp4);
    hipLaunchKernelGGL(cnn_enc_kernel, dim3(32 * MT), dim3(512), 0, stream,
                       ub, wp4, bk, out);
}